// Round 7
// baseline (171.286 us; speedup 1.0000x reference)
//
#include <hip/hip_runtime.h>
#include <hip/hip_bf16.h>

// Problem constants (from reference)
#define V 50000
#define D 128
#define B 2048
#define P 20

// Stage-1: x[B][D] = inputs[B][V] @ W_emb[D][V]^T, split-K
#define BM 128
#define BK 64
#define LDK 72                  // padded LDS row stride in bf16 (144 B, 16-B aligned)
#define NSPLIT 48               // 8 XCDs x 6 splits; grid 16*48 = 768 = exactly 3 blocks/CU
#define KC 1056                 // full splits: 17 steps of 64 (last half-empty); split 47: 368 k
#define VPAD (NSPLIT * KC)      // 50688 zero-padded bf16 W (covers all unguarded W reads)
#define NMT (B / BM)            // 16

typedef float  f32x4  __attribute__((ext_vector_type(4)));
typedef short  bf16x8 __attribute__((ext_vector_type(8)));
typedef unsigned int uint4v __attribute__((ext_vector_type(4)));
typedef unsigned int uint2v __attribute__((ext_vector_type(2)));

// truncating fp32->bf16 pack of two floats into one u32 (low = a, high = b)
__device__ __forceinline__ unsigned int pk2(float a, float b) {
    return (__float_as_uint(b) & 0xFFFF0000u) | (__float_as_uint(a) >> 16);
}
// RNE fp32->bf16
__device__ __forceinline__ unsigned short f2bf(float f) {
    unsigned int u = __float_as_uint(f);
    return (unsigned short)((u + 0x7FFFu + ((u >> 16) & 1u)) >> 16);
}

// ---------------- pre-pass: W_emb fp32 [D][V] -> bf16 [D][VPAD], zero pad ----------------
__global__ __launch_bounds__(256)
void w2v_wcast(const float* __restrict__ Wemb, unsigned short* __restrict__ Wb) {
    const size_t t = (size_t)blockIdx.x * 256 + threadIdx.x;
    const size_t n = (size_t)D * VPAD / 8;       // 811008 -> grid 3168 exact
    if (t >= n) return;
    const size_t base = t * 8;                   // padded coords, 8-aligned
    const int d = (int)(base / VPAD);
    const int k = (int)(base % VPAD);
    uint4v u = {0u, 0u, 0u, 0u};
    if (k + 8 <= V) {                            // V%8==0 -> chunk fully valid or fully pad
        const f32x4* src = reinterpret_cast<const f32x4*>(Wemb + (size_t)d * V + k);
        f32x4 v0 = src[0], v1 = src[1];
        u.x = pk2(v0[0], v0[1]); u.y = pk2(v0[2], v0[3]);
        u.z = pk2(v1[0], v1[1]); u.w = pk2(v1[2], v1[3]);
    }
    *reinterpret_cast<uint4v*>(Wb + (size_t)d * VPAD + k) = u;
}

// ---------------- stage 1: split-K GEMM, deep reg-staged (R2 structure, lean traffic) ----
// Per step: issue A 32 KB (8 float4/thread) + W 16 KB (2 uint4/thread... 4 iters) plain
// loads -> pack -> ds_write; barrier; 32 MFMA; barrier. ~144 KB/CU in flight (3 blocks).
template<int FAST>
__global__ __launch_bounds__(256, 3)
void w2v_gemm(const float* __restrict__ Ain, const void* __restrict__ Wsrc,
              void* __restrict__ part) {
    __shared__ unsigned short Sm[2 * BM * LDK];   // 36 KB: As=[0,18K), Ws=[18K,36K)
    unsigned short* As = Sm;
    unsigned short* Ws = Sm + BM * LDK;

    // XCD-aware mapping: the 16 m-blocks of a split share one XCD
    const int i   = blockIdx.x;            // 0..767
    const int xcd = i & 7;
    const int q   = i >> 3;                // 0..95
    const int s   = xcd * 6 + (q >> 4);    // 0..47
    const int mt  = q & 15;
    const int m0  = mt * BM;
    const int k0  = s * KC;
    const int k1  = (k0 + KC < V) ? (k0 + KC) : V;
    const int nsteps = (k1 - k0 + 63) >> 6;       // 17 (split 47: 6)

    const int tid  = threadIdx.x;
    const int lane = tid & 63;
    const int wid  = tid >> 6;
    const int w32  = wid * 32;             // wave owns rows [w32, w32+32)
    const int fr   = lane & 15;
    const int kg4  = lane >> 4;

    f32x4 acc[2][8] = {};

    const unsigned short* Wb = (const unsigned short*)Wsrc;    // FAST: bf16 [D][VPAD]
    const float*          Wf = (const float*)Wsrc;             // !FAST: fp32 [D][V]

    for (int t = 0; t < nsteps; ++t) {
        const int ks = k0 + t * 64;

        // ---- stage A: 2048 float4 slots; per instr 4 rows x 256 B contiguous ----
#pragma unroll
        for (int it = 0; it < 8; ++it) {
            const int slot = tid + it * 256;       // 0..2047
            const int row  = slot >> 4;
            const int kv   = slot & 15;
            const int kg   = ks + kv * 4;
            f32x4 v = {0.f, 0.f, 0.f, 0.f};
            if (kg + 4 <= k1)                      // 4-granular guard handles all tails
                v = *reinterpret_cast<const f32x4*>(Ain + (size_t)(m0 + row) * V + kg);
            uint2v u;
            u.x = pk2(v[0], v[1]);
            u.y = pk2(v[2], v[3]);
            *reinterpret_cast<uint2v*>(&As[row * LDK + kv * 4]) = u;   // 8-B aligned
        }
        // ---- stage W: 1024 16-B slots; per instr 8 rows x 128 B contiguous ----
#pragma unroll
        for (int it = 0; it < 4; ++it) {
            const int slot = tid + it * 256;       // 0..1023
            const int d    = slot >> 3;
            const int c8   = slot & 7;
            const int kg   = ks + c8 * 8;
            uint4v u;
            if (FAST) {
                u = *reinterpret_cast<const uint4v*>(Wb + (size_t)d * VPAD + kg);  // padded
            } else {
                u.x = 0u; u.y = 0u; u.z = 0u; u.w = 0u;
                if (kg + 8 <= V) {
                    const f32x4* sp = reinterpret_cast<const f32x4*>(Wf + (size_t)d * V + kg);
                    f32x4 v0 = sp[0], v1 = sp[1];
                    u.x = pk2(v0[0], v0[1]); u.y = pk2(v0[2], v0[3]);
                    u.z = pk2(v1[0], v1[1]); u.w = pk2(v1[2], v1[3]);
                }
            }
            *reinterpret_cast<uint4v*>(&Ws[d * LDK + c8 * 8]) = u;     // 16-B aligned
        }
        __syncthreads();

        // ---- compute: 2 k-halves x 16 MFMA ----
#pragma unroll
        for (int kk = 0; kk < BK; kk += 32) {
            const int kfo = kk + kg4 * 8;
            bf16x8 af[2];
#pragma unroll
            for (int m = 0; m < 2; ++m)
                af[m] = *reinterpret_cast<const bf16x8*>(&As[(w32 + m * 16 + fr) * LDK + kfo]);
#pragma unroll
            for (int n = 0; n < 8; ++n) {
                const bf16x8 wf = *reinterpret_cast<const bf16x8*>(&Ws[(n * 16 + fr) * LDK + kfo]);
                acc[0][n] = __builtin_amdgcn_mfma_f32_16x16x32_bf16(af[0], wf, acc[0][n], 0, 0, 0);
                acc[1][n] = __builtin_amdgcn_mfma_f32_16x16x32_bf16(af[1], wf, acc[1][n], 0, 0, 0);
            }
        }
        __syncthreads();
    }

    // ---- epilogue (C/D layout: col = lane&15, row = kg4*4 + jj) ----
    if (!FAST) {
        float* outp = (float*)part;        // fp32 [B][D], atomic accumulate
#pragma unroll
        for (int m = 0; m < 2; ++m) {
            const int r0 = m0 + w32 + m * 16 + kg4 * 4;
#pragma unroll
            for (int n = 0; n < 8; ++n) {
                const int c = n * 16 + fr;
#pragma unroll
                for (int jj = 0; jj < 4; ++jj)
                    atomicAdd(&outp[(size_t)(r0 + jj) * D + c], acc[m][n][jj]);
            }
        }
        return;
    }
    unsigned short* Cs = Sm;               // [128][128] bf16 = 32 KB (fits in 36)
#pragma unroll
    for (int m = 0; m < 2; ++m) {
        const int r0 = w32 + m * 16 + kg4 * 4;
#pragma unroll
        for (int n = 0; n < 8; ++n) {
            const int c = n * 16 + fr;
#pragma unroll
            for (int jj = 0; jj < 4; ++jj)
                Cs[(r0 + jj) * 128 + c] = f2bf(acc[m][n][jj]);
        }
    }
    __syncthreads();
    char* dstb = (char*)part + ((size_t)s * B + m0) * (D * 2);   // [s][b][d] bf16
#pragma unroll
    for (int it = 0; it < 8; ++it) {
        const int off = (it * 256 + tid) * 16;                   // 32 KB coalesced
        uint4v v = *reinterpret_cast<const uint4v*>((char*)Sm + off);
        *reinterpret_cast<uint4v*>(dstb + off) = v;
    }
}

// ---------------- stage 2: reduce splits + gathered cls dots + BCE + mean ----------------
__global__ __launch_bounds__(256)
void w2v_loss(const void* __restrict__ part, int part_bf16,
              const float* __restrict__ Wcls, const int* __restrict__ pathIdx,
              const float* __restrict__ codes, const float* __restrict__ mask,
              float* __restrict__ out) {
    const int lane = threadIdx.x & 63;
    const int wid  = threadIdx.x >> 6;
    const int b    = blockIdx.x * 4 + wid;     // one wave per sample

    float x0 = 0.f, x1 = 0.f;                  // x[b][2*lane], x[b][2*lane+1]
    if (part_bf16) {
        const unsigned* pb = (const unsigned*)part;   // 64 u32 per [s][b] row
#pragma unroll 8
        for (int s = 0; s < NSPLIT; ++s) {
            unsigned u = pb[((size_t)s * B + b) * 64 + lane];
            x0 += __uint_as_float(u << 16);
            x1 += __uint_as_float(u & 0xFFFF0000u);
        }
    } else {
        const float* pf = (const float*)part;         // [B][D] fp32, pre-reduced
        const float2 v = *reinterpret_cast<const float2*>(&pf[(size_t)b * D + lane * 2]);
        x0 = v.x; x1 = v.y;
    }

    float lsum = 0.f, msum = 0.f;
#pragma unroll
    for (int p = 0; p < P; ++p) {
        int node = pathIdx[b * P + p];
        const float2 w = *reinterpret_cast<const float2*>(&Wcls[(size_t)node * D + lane * 2]);
        float d = x0 * w.x + x1 * w.y;
#pragma unroll
        for (int off = 1; off < 64; off <<= 1)
            d += __shfl_xor(d, off, 64);
        float t  = codes[b * P + p];
        float mm = mask[b * P + p];
        float loss = fmaxf(d, 0.f) - d * t + log1pf(__expf(-fabsf(d)));
        lsum += loss * mm;
        msum += mm;
    }
    float per = (msum > 0.f) ? (lsum / msum) : 0.f;

    __shared__ float wsum[4];
    if (lane == 0) wsum[wid] = per;
    __syncthreads();
    if (threadIdx.x == 0) {
        float ssum = wsum[0] + wsum[1] + wsum[2] + wsum[3];
        atomicAdd(out, ssum * (1.0f / (float)B));
    }
}

extern "C" void kernel_launch(void* const* d_in, const int* in_sizes, int n_in,
                              void* d_out, int out_size, void* d_ws, size_t ws_size,
                              hipStream_t stream) {
    const float* inputs = (const float*)d_in[0];   // [B,V]
    const float* W_emb  = (const float*)d_in[1];   // [D,V]
    const float* W_cls  = (const float*)d_in[2];   // [V,D]
    const int*   path   = (const int*)  d_in[3];   // [B,P]
    const float* codes  = (const float*)d_in[4];   // [B,P]
    const float* mask   = (const float*)d_in[5];   // [B,P]
    float* out = (float*)d_out;

    hipMemsetAsync(d_out, 0, sizeof(float), stream);

    const size_t wb_bytes  = (size_t)D * VPAD * 2;                    // ~13.0 MB
    const size_t part_off  = (wb_bytes + 255) & ~(size_t)255;
    const size_t part_need = part_off + (size_t)NSPLIT * B * D * 2;   // ~38.2 MB

    if (ws_size >= part_need) {
        unsigned short* Wb = (unsigned short*)d_ws;
        char* partp = (char*)d_ws + part_off;
        w2v_wcast<<<dim3((unsigned)((size_t)D * VPAD / 8 / 256)), dim3(256), 0, stream>>>(W_emb, Wb);
        w2v_gemm<1><<<dim3(NMT * NSPLIT), dim3(256), 0, stream>>>(inputs, Wb, partp);
        w2v_loss<<<dim3(B / 4), dim3(256), 0, stream>>>(partp, 1, W_cls, path, codes, mask, out);
    } else {
        hipMemsetAsync(d_ws, 0, (size_t)B * D * sizeof(float), stream);
        w2v_gemm<0><<<dim3(NMT * NSPLIT), dim3(256), 0, stream>>>(inputs, W_emb, d_ws);
        w2v_loss<<<dim3(B / 4), dim3(256), 0, stream>>>(d_ws, 0, W_cls, path, codes, mask, out);
    }
}

// Round 8
// 143.573 us; speedup vs baseline: 1.1930x; 1.1930x over previous
//
#include <hip/hip_runtime.h>
#include <hip/hip_bf16.h>

// Problem constants (from reference)
#define V 50000
#define D 128
#define B 2048
#define P 20

// Stage-1: x[B][D] = inputs[B][V] @ W_emb[D][V]^T, split-K
#define BM 128
#define BK 64
#define NSPLIT 48               // 8 XCDs x 6 splits; grid 16*48 = 768 = exactly 3 blocks/CU
#define KC 1056                 // full splits: 17 steps of 64; split 47: 368 k = 6 steps
#define VPAD (NSPLIT * KC)      // 50688 zero-padded bf16 W (covers all unguarded W reads)
#define NMT (B / BM)            // 16

typedef float  f32x4  __attribute__((ext_vector_type(4)));
typedef short  bf16x8 __attribute__((ext_vector_type(8)));
typedef unsigned int uint4v __attribute__((ext_vector_type(4)));

// truncating fp32->bf16 pack of two floats into one u32 (low = a, high = b)
__device__ __forceinline__ unsigned int pk2(float a, float b) {
    return (__float_as_uint(b) & 0xFFFF0000u) | (__float_as_uint(a) >> 16);
}
// RNE fp32->bf16
__device__ __forceinline__ unsigned short f2bf(float f) {
    unsigned int u = __float_as_uint(f);
    return (unsigned short)((u + 0x7FFFu + ((u >> 16) & 1u)) >> 16);
}

// ---------------- pre-pass: W_emb fp32 [D][V] -> bf16 [D][VPAD], zero pad ----------------
__global__ __launch_bounds__(256)
void w2v_wcast(const float* __restrict__ Wemb, unsigned short* __restrict__ Wb) {
    const size_t t = (size_t)blockIdx.x * 256 + threadIdx.x;
    const size_t n = (size_t)D * VPAD / 8;       // 811008 -> grid 3168 exact
    if (t >= n) return;
    const size_t base = t * 8;                   // padded coords, 8-aligned
    const int d = (int)(base / VPAD);
    const int k = (int)(base % VPAD);
    uint4v u = {0u, 0u, 0u, 0u};
    if (k + 8 <= V) {                            // V%8==0 -> chunk fully valid or fully pad
        const f32x4* src = reinterpret_cast<const f32x4*>(Wemb + (size_t)d * V + k);
        f32x4 v0 = src[0], v1 = src[1];
        u.x = pk2(v0[0], v0[1]); u.y = pk2(v0[2], v0[3]);
        u.z = pk2(v1[0], v1[1]); u.w = pk2(v1[2], v1[3]);
    }
    *reinterpret_cast<uint4v*>(Wb + (size_t)d * VPAD + k) = u;
}

// ---------------- stage 1: split-K GEMM, issue-early reg pipeline, raw barriers ----------
// Per step: writeLDS(regs[t]) ; lgkm-barrier ; issue loads(t+1) ; 32 MFMA ; lgkm-barrier.
// Loads stay in flight across compute + barriers (no vmcnt(0) in loop): ~144 KB/CU.
template<int FAST>
__global__ __launch_bounds__(256, 3)
void w2v_gemm(const float* __restrict__ Ain, const void* __restrict__ Wsrc,
              void* __restrict__ part) {
    __shared__ unsigned short Sm[2 * BM * BK];   // 32 KB: As=[0,16K), Ws=[16K,32K)
    char* AsB = (char*)Sm;
    char* WsB = (char*)(Sm + BM * BK);

    // XCD-aware mapping: the 16 m-blocks of a split share one XCD
    const int i   = blockIdx.x;            // 0..767
    const int xcd = i & 7;
    const int q   = i >> 3;                // 0..95
    const int s   = xcd * 6 + (q >> 4);    // 0..47
    const int mt  = q & 15;
    const int m0  = mt * BM;
    const int k0  = s * KC;
    const int k1  = (k0 + KC < V) ? (k0 + KC) : V;   // k1 % 16 == 0 always
    const int nsteps = (k1 - k0 + 63) >> 6;          // 17 (split 47: 6)

    const int tid  = threadIdx.x;
    const int lane = tid & 63;
    const int wid  = tid >> 6;
    const int w32  = wid * 32;             // wave owns output rows [w32, w32+32)
    const int fr   = lane & 15;
    const int kg4  = lane >> 4;

    f32x4 acc[2][8] = {};

    // staging geometry: slot = tid + it*256; row = rbase + it*32; c8 = tid&7 (it-invariant)
    const int rbase = tid >> 3;
    const int c8    = tid & 7;
    const int c8x   = c8 ^ (rbase & 7);    // swizzled chunk (row&7 is it-invariant)
    const float* aBase = Ain + (size_t)(m0 + rbase) * V + c8 * 8;
    const unsigned short* Wb = (const unsigned short*)Wsrc;    // FAST: bf16 [D][VPAD]
    const float*          Wf = (const float*)Wsrc;             // !FAST: fp32 [D][V]
    const unsigned short* wBaseB = Wb + (size_t)rbase * VPAD + c8 * 8;
    const float*          wBaseF = Wf + (size_t)rbase * V + c8 * 8;

    // staged registers (static indices only)
    f32x4 aR[8];                           // A: 4 slots x 2 f32x4
    uint4v wR[4];                          // W: 4 slots x 16 B bf16
    f32x4 wRf[8];                          // !FAST W fp32 staging

    auto loadregs = [&](int ks) {
        const bool ag = (ks + c8 * 8 + 8 <= k1);       // 8-granular (k1%16==0)
#pragma unroll
        for (int it = 0; it < 4; ++it) {
            const float* ap = aBase + (size_t)(it * 32) * V + ks;
            if (ag) {
                aR[it * 2]     = *reinterpret_cast<const f32x4*>(ap);
                aR[it * 2 + 1] = *reinterpret_cast<const f32x4*>(ap + 4);
            } else {
                aR[it * 2] = f32x4{0.f, 0.f, 0.f, 0.f};
                aR[it * 2 + 1] = f32x4{0.f, 0.f, 0.f, 0.f};
            }
        }
        if (FAST) {
#pragma unroll
            for (int it = 0; it < 4; ++it)             // VPAD zero-pad: no guard
                wR[it] = *reinterpret_cast<const uint4v*>(wBaseB + (size_t)(it * 32) * VPAD + ks);
        } else {
            const bool wg = (ks + c8 * 8 + 8 <= V);
#pragma unroll
            for (int it = 0; it < 4; ++it) {
                const float* wp = wBaseF + (size_t)(it * 32) * V + ks;
                if (wg) {
                    wRf[it * 2]     = *reinterpret_cast<const f32x4*>(wp);
                    wRf[it * 2 + 1] = *reinterpret_cast<const f32x4*>(wp + 4);
                } else {
                    wRf[it * 2] = f32x4{0.f, 0.f, 0.f, 0.f};
                    wRf[it * 2 + 1] = f32x4{0.f, 0.f, 0.f, 0.f};
                }
            }
        }
    };

    auto writeLDS = [&]() {
#pragma unroll
        for (int it = 0; it < 4; ++it) {
            const unsigned dst = (unsigned)((rbase + it * 32) * 128) + (unsigned)(c8x * 16);
            uint4v ua;
            ua.x = pk2(aR[it * 2][0], aR[it * 2][1]);
            ua.y = pk2(aR[it * 2][2], aR[it * 2][3]);
            ua.z = pk2(aR[it * 2 + 1][0], aR[it * 2 + 1][1]);
            ua.w = pk2(aR[it * 2 + 1][2], aR[it * 2 + 1][3]);
            *reinterpret_cast<uint4v*>(AsB + dst) = ua;
            uint4v uw;
            if (FAST) {
                uw = wR[it];
            } else {
                uw.x = pk2(wRf[it * 2][0], wRf[it * 2][1]);
                uw.y = pk2(wRf[it * 2][2], wRf[it * 2][3]);
                uw.z = pk2(wRf[it * 2 + 1][0], wRf[it * 2 + 1][1]);
                uw.w = pk2(wRf[it * 2 + 1][2], wRf[it * 2 + 1][3]);
            }
            *reinterpret_cast<uint4v*>(WsB + dst) = uw;
        }
    };

    loadregs(k0);                          // prologue

    for (int t = 0; t < nsteps; ++t) {
        writeLDS();                        // vmcnt waits land here (issued a phase ago)
        asm volatile("s_waitcnt lgkmcnt(0)" ::: "memory");
        __builtin_amdgcn_s_barrier();      // raw: no vmcnt drain
        if (t + 1 < nsteps) loadregs(k0 + (t + 1) * 64);   // in flight through compute
        // ---- compute: 2 k-halves x 16 MFMA from swizzled LDS ----
#pragma unroll
        for (int kk = 0; kk < BK; kk += 32) {
            const int cbase = (kk >> 3) + kg4;             // chunk 0..7
            bf16x8 af[2];
#pragma unroll
            for (int m = 0; m < 2; ++m) {
                const int r = w32 + m * 16 + fr;
                af[m] = *reinterpret_cast<const bf16x8*>(
                    AsB + r * 128 + ((cbase ^ (r & 7)) << 4));
            }
#pragma unroll
            for (int n = 0; n < 8; ++n) {
                const int r = n * 16 + fr;
                const bf16x8 wf = *reinterpret_cast<const bf16x8*>(
                    WsB + r * 128 + ((cbase ^ (r & 7)) << 4));
                acc[0][n] = __builtin_amdgcn_mfma_f32_16x16x32_bf16(af[0], wf, acc[0][n], 0, 0, 0);
                acc[1][n] = __builtin_amdgcn_mfma_f32_16x16x32_bf16(af[1], wf, acc[1][n], 0, 0, 0);
            }
        }
        asm volatile("s_waitcnt lgkmcnt(0)" ::: "memory");
        __builtin_amdgcn_s_barrier();      // protect LDS overwrite; vmcnt stays in flight
    }

    // ---- epilogue (C/D layout: col = lane&15, row = kg4*4 + jj) ----
    if (!FAST) {
        float* outp = (float*)part;        // fp32 [B][D], atomic accumulate
#pragma unroll
        for (int m = 0; m < 2; ++m) {
            const int r0 = m0 + w32 + m * 16 + kg4 * 4;
#pragma unroll
            for (int n = 0; n < 8; ++n) {
                const int c = n * 16 + fr;
#pragma unroll
                for (int jj = 0; jj < 4; ++jj)
                    atomicAdd(&outp[(size_t)(r0 + jj) * D + c], acc[m][n][jj]);
            }
        }
        return;
    }
    unsigned short* Cs = Sm;               // [128][128] bf16 = 32 KB (exact fit)
#pragma unroll
    for (int m = 0; m < 2; ++m) {
        const int r0 = w32 + m * 16 + kg4 * 4;
#pragma unroll
        for (int n = 0; n < 8; ++n) {
            const int c = n * 16 + fr;
#pragma unroll
            for (int jj = 0; jj < 4; ++jj)
                Cs[(r0 + jj) * 128 + c] = f2bf(acc[m][n][jj]);
        }
    }
    __syncthreads();
    char* dstb = (char*)part + ((size_t)s * B + m0) * (D * 2);   // [s][b][d] bf16
#pragma unroll
    for (int it = 0; it < 8; ++it) {
        const int off = (it * 256 + tid) * 16;                   // 32 KB coalesced
        uint4v v = *reinterpret_cast<const uint4v*>((char*)Sm + off);
        *reinterpret_cast<uint4v*>(dstb + off) = v;
    }
}

// ---------------- stage 2: reduce splits + gathered cls dots + BCE + mean ----------------
__global__ __launch_bounds__(256)
void w2v_loss(const void* __restrict__ part, int part_bf16,
              const float* __restrict__ Wcls, const int* __restrict__ pathIdx,
              const float* __restrict__ codes, const float* __restrict__ mask,
              float* __restrict__ out) {
    const int lane = threadIdx.x & 63;
    const int wid  = threadIdx.x >> 6;
    const int b    = blockIdx.x * 4 + wid;     // one wave per sample

    float x0 = 0.f, x1 = 0.f;                  // x[b][2*lane], x[b][2*lane+1]
    if (part_bf16) {
        const unsigned* pb = (const unsigned*)part;   // 64 u32 per [s][b] row
#pragma unroll 8
        for (int s = 0; s < NSPLIT; ++s) {
            unsigned u = pb[((size_t)s * B + b) * 64 + lane];
            x0 += __uint_as_float(u << 16);
            x1 += __uint_as_float(u & 0xFFFF0000u);
        }
    } else {
        const float* pf = (const float*)part;         // [B][D] fp32, pre-reduced
        const float2 v = *reinterpret_cast<const float2*>(&pf[(size_t)b * D + lane * 2]);
        x0 = v.x; x1 = v.y;
    }

    float lsum = 0.f, msum = 0.f;
#pragma unroll
    for (int p = 0; p < P; ++p) {
        int node = pathIdx[b * P + p];
        const float2 w = *reinterpret_cast<const float2*>(&Wcls[(size_t)node * D + lane * 2]);
        float d = x0 * w.x + x1 * w.y;
#pragma unroll
        for (int off = 1; off < 64; off <<= 1)
            d += __shfl_xor(d, off, 64);
        float t  = codes[b * P + p];
        float mm = mask[b * P + p];
        float loss = fmaxf(d, 0.f) - d * t + log1pf(__expf(-fabsf(d)));
        lsum += loss * mm;
        msum += mm;
    }
    float per = (msum > 0.f) ? (lsum / msum) : 0.f;

    __shared__ float wsum[4];
    if (lane == 0) wsum[wid] = per;
    __syncthreads();
    if (threadIdx.x == 0) {
        float ssum = wsum[0] + wsum[1] + wsum[2] + wsum[3];
        atomicAdd(out, ssum * (1.0f / (float)B));
    }
}

extern "C" void kernel_launch(void* const* d_in, const int* in_sizes, int n_in,
                              void* d_out, int out_size, void* d_ws, size_t ws_size,
                              hipStream_t stream) {
    const float* inputs = (const float*)d_in[0];   // [B,V]
    const float* W_emb  = (const float*)d_in[1];   // [D,V]
    const float* W_cls  = (const float*)d_in[2];   // [V,D]
    const int*   path   = (const int*)  d_in[3];   // [B,P]
    const float* codes  = (const float*)d_in[4];   // [B,P]
    const float* mask   = (const float*)d_in[5];   // [B,P]
    float* out = (float*)d_out;

    hipMemsetAsync(d_out, 0, sizeof(float), stream);

    const size_t wb_bytes  = (size_t)D * VPAD * 2;                    // ~13.0 MB
    const size_t part_off  = (wb_bytes + 255) & ~(size_t)255;
    const size_t part_need = part_off + (size_t)NSPLIT * B * D * 2;   // ~38.2 MB

    if (ws_size >= part_need) {
        unsigned short* Wb = (unsigned short*)d_ws;
        char* partp = (char*)d_ws + part_off;
        w2v_wcast<<<dim3((unsigned)((size_t)D * VPAD / 8 / 256)), dim3(256), 0, stream>>>(W_emb, Wb);
        w2v_gemm<1><<<dim3(NMT * NSPLIT), dim3(256), 0, stream>>>(inputs, Wb, partp);
        w2v_loss<<<dim3(B / 4), dim3(256), 0, stream>>>(partp, 1, W_cls, path, codes, mask, out);
    } else {
        hipMemsetAsync(d_ws, 0, (size_t)B * D * sizeof(float), stream);
        w2v_gemm<0><<<dim3(NMT * NSPLIT), dim3(256), 0, stream>>>(inputs, W_emb, d_ws);
        w2v_loss<<<dim3(B / 4), dim3(256), 0, stream>>>(d_ws, 0, W_cls, path, codes, mask, out);
    }
}